// Round 8
// baseline (291.945 us; speedup 1.0000x reference)
//
#include <hip/hip_runtime.h>
#include <hip/hip_fp16.h>

typedef __attribute__((ext_vector_type(4)))  int   i32x4;
typedef __attribute__((ext_vector_type(16))) int   i32x16;

#define ALPHA 32
#define BM 256
#define BN 128
#define BK 64

// Tiled int8 workspace layout (every MFMA fragment = contiguous 1KB):
//   addr(row,k) = (row>>5)*(32*K) + (k>>4)*512 + (row&31)*16 + (k&15)

// ---------------- kernel A: top-32 of |act_max| + keep-bitmask ----------------
__global__ __launch_bounds__(256) void topk_kernel(const float* __restrict__ act_max,
                                                   int* __restrict__ idx_out,
                                                   unsigned* __restrict__ tbits,
                                                   int K) {
  __shared__ float v[4096];
  __shared__ float rv[4];
  __shared__ int   ri[4];
  __shared__ unsigned bits[128];
  const int t = threadIdx.x;
  for (int i = t; i < K; i += 256) v[i] = fabsf(act_max[i]);
  for (int i = t; i < K / 32; i += 256) bits[i] = 0xFFFFFFFFu;
  __syncthreads();
  for (int sel = 0; sel < ALPHA; ++sel) {
    float bv = -1.f; int bi = 0;
    for (int i = t; i < K; i += 256) {
      float x = v[i];
      if (x > bv) { bv = x; bi = i; }
    }
    for (int m = 1; m < 64; m <<= 1) {
      float ov = __shfl_xor(bv, m);
      int   oi = __shfl_xor(bi, m);
      if (ov > bv || (ov == bv && oi < bi)) { bv = ov; bi = oi; }
    }
    if ((t & 63) == 0) { rv[t >> 6] = bv; ri[t >> 6] = bi; }
    __syncthreads();
    if (t == 0) {
      for (int u = 1; u < 4; ++u)
        if (rv[u] > bv || (rv[u] == bv && ri[u] < bi)) { bv = rv[u]; bi = ri[u]; }
      idx_out[sel] = bi;
      v[bi] = -2.f;
      bits[bi >> 5] &= ~(1u << (bi & 31));
    }
    __syncthreads();
  }
  for (int i = t; i < K / 32; i += 256) tbits[i] = bits[i];
}

// ------------- kernel B: 8-rows-per-block quantization + gather -------------
__global__ __launch_bounds__(256) void quant8_kernel(
    const float* __restrict__ srcW, const float* __restrict__ srcX,
    const unsigned* __restrict__ tbits, const int* __restrict__ idxg,
    signed char* __restrict__ wq, signed char* __restrict__ xq,
    _Float16* __restrict__ wmax, _Float16* __restrict__ xmax,
    float* __restrict__ wuf, float* __restrict__ xuf,
    int nbw, int K, int N, int M) {
  const int t = threadIdx.x, lane = t & 63, w = t >> 6;
  const int b = blockIdx.x;
  const float* src; signed char* q; _Float16* smax; float* unq; int r0, R;
  if (b < nbw) { src = srcW; q = wq; smax = wmax; unq = wuf; r0 = b * 8; R = N; }
  else         { src = srcX; q = xq; smax = xmax; unq = xuf; r0 = (b - nbw) * 8; R = M; }
  __shared__ unsigned bits[128];
  __shared__ signed char qt[8 * 4096];   // [row][swizzled chunk]
  for (int i = t; i < 128; i += 256) bits[i] = tbits[i];
  __syncthreads();
  const int shft = (lane & 7) * 4;
#pragma unroll
  for (int g = 0; g < 2; ++g) {
    const int rl = w + 4 * g;            // local row 0..7
    const float4* srow = (const float4*)(src + (size_t)(r0 + rl) * K);
    float4 v[16];
    float am = 0.f;
#pragma unroll
    for (int j = 0; j < 16; ++j) {       // wave reads 1KB contiguous per instr
      float4 x = srow[j * 64 + lane];
      unsigned b4 = bits[j * 8 + (lane >> 3)] >> shft;
      if (!(b4 & 1u)) x.x = 0.f;
      if (!(b4 & 2u)) x.y = 0.f;
      if (!(b4 & 4u)) x.z = 0.f;
      if (!(b4 & 8u)) x.w = 0.f;
      v[j] = x;
      am = fmaxf(am, fmaxf(fmaxf(fabsf(x.x), fabsf(x.y)), fmaxf(fabsf(x.z), fabsf(x.w))));
    }
#pragma unroll
    for (int m = 1; m < 64; m <<= 1) am = fmaxf(am, __shfl_xor(am, m));
    const _Float16 sh = (_Float16)(am / 127.0f);   // RTN to fp16, like astype(float16)
    const float s = (float)sh;
    if (lane == 0) smax[r0 + rl] = sh;
    signed char* row = qt + rl * 4096;
#pragma unroll
    for (int j = 0; j < 16; ++j) {
      float4 x = v[j];
      char4 c;
      c.x = (signed char)(x.x / s);      // fp32 divide + trunc = astype(int8)
      c.y = (signed char)(x.y / s);
      c.z = (signed char)(x.z / s);
      c.w = (signed char)(x.w / s);
      const int c2 = j * 16 + (lane >> 2);
      *(char4*)(row + ((c2 ^ rl) << 4) + (lane & 3) * 4) = c;   // 2-way max (free)
    }
  }
  __syncthreads();
  // store phase: 2048 int4, 128B-contiguous global segments
  const size_t pbase = (size_t)(r0 >> 5) * 32 * K + (size_t)(r0 & 31) * 16;
#pragma unroll
  for (int i = 0; i < 8; ++i) {
    const int s2 = i * 256 + t;
    const int c2 = s2 >> 3, rl = s2 & 7;
    int4 d = *(const int4*)(qt + rl * 4096 + ((c2 ^ rl) << 4));
    *(int4*)(q + pbase + (size_t)c2 * 512 + rl * 16) = d;
  }
  { // outlier gather: 32 idx x 8 rows
    const int j = t >> 3, rl = t & 7;
    unq[(size_t)j * R + r0 + rl] = src[(size_t)(r0 + rl) * K + idxg[j]];
  }
}

// ---- kernel D: i8 GEMM, ALL-REGISTER main loop (ablation of LDS+barriers).
//      Every fragment is a contiguous 1KB global_load_dwordx4 from the tiled
//      workspace; 1-tile register prefetch; no LDS, no barriers, no inline
//      waitcnt -- compiler-exact vmcnt bookkeeping. Waves free-run (T5 regime).
typedef struct { i32x4 a[4][2]; i32x4 b[2][2]; } Frag;

__global__ __launch_bounds__(256, 2) void gemm_kernel(
    const signed char* __restrict__ xq, const signed char* __restrict__ wq,
    const _Float16* __restrict__ xmax, const _Float16* __restrict__ wmax,
    const float* __restrict__ xuf,   // [ALPHA][M]
    const float* __restrict__ wuf,   // [ALPHA][N]
    const float* __restrict__ bias,  // [N]
    float* __restrict__ out, int M, int N, int K) {
  __shared__ struct { float xu[ALPHA * BM]; float wu[ALPHA * BN]; } sme;  // 48 KB (epilogue only)
  __shared__ _Float16 xmh[BM];
  __shared__ _Float16 wmh[BN];
  __shared__ float    bl[BN];

  const int t = threadIdx.x;
  // XCD-aware swizzle: 1024 blocks, 8 XCDs -> each XCD owns 4 consecutive bx.
  const int bid = blockIdx.y * gridDim.x + blockIdx.x;
  const int xcd = bid & 7, loc = bid >> 3;
  const int bxi = xcd * 4 + (loc & 3);
  const int byi = loc >> 2;
  const int bm0 = byi * BM;
  const int bn0 = bxi * BN;
  const int lane = t & 63, w = t >> 6;
  const int wm = w >> 1, wn = w & 1;       // 2x2 waves, wave tile 128x64
  const int hi = lane >> 5, l31 = lane & 31;

  i32x16 acc[4][2] = {};

  const size_t P32 = (size_t)32 * K;       // panel stride (32 rows)
  // fragment bases: lane-linear 16B within a contiguous 1KB per fragment
  const signed char* const aF = xq + ((size_t)(bm0 >> 5) + wm * 4) * P32 + hi * 512 + l31 * 16;
  const signed char* const bF = wq + ((size_t)(bn0 >> 5) + wn * 2) * P32 + hi * 512 + l31 * 16;

#define LOADT(P, KT)                                                              \
  {                                                                               \
    const size_t ko = (size_t)(KT) * 2048;                                        \
    _Pragma("unroll") for (int mi = 0; mi < 4; ++mi)                              \
      _Pragma("unroll") for (int ks = 0; ks < 2; ++ks)                            \
        P.a[mi][ks] = *(const i32x4*)(aF + (size_t)mi * P32 + ko + ks * 1024);    \
    _Pragma("unroll") for (int ni = 0; ni < 2; ++ni)                              \
      _Pragma("unroll") for (int ks = 0; ks < 2; ++ks)                            \
        P.b[ni][ks] = *(const i32x4*)(bF + (size_t)ni * P32 + ko + ks * 1024);    \
  }

#define MFMAT(P)                                                                  \
  {                                                                               \
    __builtin_amdgcn_s_setprio(1);                                                \
    _Pragma("unroll") for (int ks = 0; ks < 2; ++ks)                              \
      _Pragma("unroll") for (int mi = 0; mi < 4; ++mi)                            \
        _Pragma("unroll") for (int ni = 0; ni < 2; ++ni)                          \
          acc[mi][ni] = __builtin_amdgcn_mfma_i32_32x32x32_i8(                    \
              P.a[mi][ks], P.b[ni][ks], acc[mi][ni], 0, 0, 0);                    \
    __builtin_amdgcn_s_setprio(0);                                                \
  }

  const int NT = K >> 6;   // 64 (even)
  Frag pA, pB;
  LOADT(pA, 0);
  int kt = 0;
  for (; kt < NT - 2; kt += 2) {
    LOADT(pB, kt + 1);     // issued one MFMA-cluster ahead of use
    MFMAT(pA);
    LOADT(pA, kt + 2);
    MFMAT(pB);
  }
  LOADT(pB, NT - 1);
  MFMAT(pA);
  MFMAT(pB);
#undef LOADT
#undef MFMAT

  __syncthreads();
  // ---- epilogue staging ----
  {
    const float4* xs = (const float4*)xuf;
    float4* xl = (float4*)sme.xu;
#pragma unroll
    for (int i = 0; i < 8; ++i) {   // 2048 float4
      int p = i * 256 + t;
      int j = p >> 6, r4 = p & 63;
      xl[p] = xs[(size_t)j * (M >> 2) + (bm0 >> 2) + r4];
    }
    const float4* wsrc = (const float4*)wuf;
    float4* wl = (float4*)sme.wu;
#pragma unroll
    for (int i = 0; i < 4; ++i) {   // 1024 float4
      int p = i * 256 + t;
      int j = p >> 5, r4 = p & 31;
      wl[p] = wsrc[(size_t)j * (N >> 2) + (bn0 >> 2) + r4];
    }
    if (t < BM / 2) ((unsigned*)xmh)[t] = ((const unsigned*)(xmax + bm0))[t];
    if (t < BN / 2) ((unsigned*)wmh)[t] = ((const unsigned*)(wmax + bn0))[t];
    if (t < BN / 4) ((float4*)bl)[t] = ((const float4*)(bias + bn0))[t];
  }
  __syncthreads();

  const int c0 = wn * 64 + l31;   // column (within tile) for ni=0; ni=1 is +32
  const _Float16 wh0 = wmh[c0], wh1 = wmh[c0 + 32];
  const float bv0 = bl[c0], bv1 = bl[c0 + 32];
  const float* xul = sme.xu;      // [ALPHA][BM]
  const float* wul = sme.wu;      // [ALPHA][BN]

#pragma unroll
  for (int mi = 0; mi < 4; ++mi) {
    const int rbase = wm * 128 + mi * 32 + 4 * hi;   // + (r&3) + 8*(r>>2)
    float f0[16], f1[16];
#pragma unroll
    for (int r = 0; r < 16; ++r) {
      int row = rbase + (r & 3) + 8 * (r >> 2);
      _Float16 xh = xmh[row];
      float mx0 = (float)(_Float16)(xh * wh0);   // fp16 multiply (subnormal-correct) like ref
      float mx1 = (float)(_Float16)(xh * wh1);
      f0[r] = (float)acc[mi][0][r] * mx0 + bv0;
      f1[r] = (float)acc[mi][1][r] * mx1 + bv1;
    }
#pragma unroll 4
    for (int j = 0; j < ALPHA; ++j) {            // rank-32 fp32 outlier update
      const float4* xrow4 = (const float4*)(xul + j * BM + rbase);
      float wv0 = wul[j * BN + c0];
      float wv1 = wul[j * BN + c0 + 32];
#pragma unroll
      for (int gq = 0; gq < 4; ++gq) {
        float4 xv = xrow4[gq * 2];               // rows rbase + 8*gq .. +3
        f0[gq * 4 + 0] += xv.x * wv0;  f1[gq * 4 + 0] += xv.x * wv1;
        f0[gq * 4 + 1] += xv.y * wv0;  f1[gq * 4 + 1] += xv.y * wv1;
        f0[gq * 4 + 2] += xv.z * wv0;  f1[gq * 4 + 2] += xv.z * wv1;
        f0[gq * 4 + 3] += xv.w * wv0;  f1[gq * 4 + 3] += xv.w * wv1;
      }
    }
#pragma unroll
    for (int r = 0; r < 16; ++r) {
      int row = bm0 + rbase + (r & 3) + 8 * (r >> 2);
      size_t o = (size_t)row * N + bn0;
      out[o + c0] = f0[r];
      out[o + c0 + 32] = f1[r];
    }
  }
}

// ---------------- launch ----------------
extern "C" void kernel_launch(void* const* d_in, const int* in_sizes, int n_in,
                              void* d_out, int out_size, void* d_ws, size_t ws_size,
                              hipStream_t stream) {
  const float* x       = (const float*)d_in[0];
  const float* W       = (const float*)d_in[1];
  const float* bias    = (const float*)d_in[2];
  const float* act_max = (const float*)d_in[3];
  const int K = in_sizes[3];            // 4096
  const int N = in_sizes[1] / K;        // 4096
  const int M = in_sizes[0] / K;        // 8192
  float* out = (float*)d_out;

  char* ws = (char*)d_ws;
  size_t off = 0;
  auto take = [&](size_t b) { char* p = ws + off; off += (b + 255) & ~(size_t)255; return p; };
  signed char* wq  = (signed char*)take((size_t)N * K);
  signed char* xq  = (signed char*)take((size_t)M * K);
  _Float16* wmax   = (_Float16*)take((size_t)N * 2);
  _Float16* xmax   = (_Float16*)take((size_t)M * 2);
  float* wuf       = (float*)take((size_t)ALPHA * N * 4);
  float* xuf       = (float*)take((size_t)ALPHA * M * 4);
  int* idx         = (int*)take(ALPHA * 4);
  unsigned* tbits  = (unsigned*)take((size_t)(K / 32) * 4);

  const int nbw = N / 8, nbx = M / 8;   // 512 + 1024 = 1536 blocks
  topk_kernel<<<1, 256, 0, stream>>>(act_max, idx, tbits, K);
  quant8_kernel<<<nbw + nbx, 256, 0, stream>>>(W, x, tbits, idx, wq, xq,
                                               wmax, xmax, wuf, xuf, nbw, K, N, M);
  dim3 grid(N / BN, M / BM);
  gemm_kernel<<<grid, 256, 0, stream>>>(xq, wq, xmax, wmax, xuf, wuf, bias, out, M, N, K);
}

// Round 10
// 289.425 us; speedup vs baseline: 1.0087x; 1.0087x over previous
//
#include <hip/hip_runtime.h>
#include <hip/hip_fp16.h>

typedef __attribute__((ext_vector_type(4)))  int   i32x4;
typedef __attribute__((ext_vector_type(16))) int   i32x16;

#define ALPHA 32
#define BM 256
#define BN 128
#define BK 64

// Tiled int8 workspace layout (matches LDS staging & fragment reads):
//   addr(row,k) = (row>>5)*(32*K) + (k>>4)*512 + (row&31)*16 + (k&15)

// ---------------- kernel A: top-32 of |act_max| + keep-bitmask ----------------
__global__ __launch_bounds__(256) void topk_kernel(const float* __restrict__ act_max,
                                                   int* __restrict__ idx_out,
                                                   unsigned* __restrict__ tbits,
                                                   int K) {
  __shared__ float v[4096];
  __shared__ float rv[4];
  __shared__ int   ri[4];
  __shared__ unsigned bits[128];
  const int t = threadIdx.x;
  for (int i = t; i < K; i += 256) v[i] = fabsf(act_max[i]);
  for (int i = t; i < K / 32; i += 256) bits[i] = 0xFFFFFFFFu;
  __syncthreads();
  for (int sel = 0; sel < ALPHA; ++sel) {
    float bv = -1.f; int bi = 0;
    for (int i = t; i < K; i += 256) {
      float x = v[i];
      if (x > bv) { bv = x; bi = i; }
    }
    for (int m = 1; m < 64; m <<= 1) {
      float ov = __shfl_xor(bv, m);
      int   oi = __shfl_xor(bi, m);
      if (ov > bv || (ov == bv && oi < bi)) { bv = ov; bi = oi; }
    }
    if ((t & 63) == 0) { rv[t >> 6] = bv; ri[t >> 6] = bi; }
    __syncthreads();
    if (t == 0) {
      for (int u = 1; u < 4; ++u)
        if (rv[u] > bv || (rv[u] == bv && ri[u] < bi)) { bv = rv[u]; bi = ri[u]; }
      idx_out[sel] = bi;
      v[bi] = -2.f;
      bits[bi >> 5] &= ~(1u << (bi & 31));
    }
    __syncthreads();
  }
  for (int i = t; i < K / 32; i += 256) tbits[i] = bits[i];
}

// ------------- kernel B: 8-rows-per-block quantization + gather -------------
__global__ __launch_bounds__(256) void quant8_kernel(
    const float* __restrict__ srcW, const float* __restrict__ srcX,
    const unsigned* __restrict__ tbits, const int* __restrict__ idxg,
    signed char* __restrict__ wq, signed char* __restrict__ xq,
    _Float16* __restrict__ wmax, _Float16* __restrict__ xmax,
    float* __restrict__ wuf, float* __restrict__ xuf,
    int nbw, int K, int N, int M) {
  const int t = threadIdx.x, lane = t & 63, w = t >> 6;
  const int b = blockIdx.x;
  const float* src; signed char* q; _Float16* smax; float* unq; int r0, R;
  if (b < nbw) { src = srcW; q = wq; smax = wmax; unq = wuf; r0 = b * 8; R = N; }
  else         { src = srcX; q = xq; smax = xmax; unq = xuf; r0 = (b - nbw) * 8; R = M; }
  __shared__ unsigned bits[128];
  __shared__ signed char qt[8 * 4096];   // [row][swizzled chunk]
  for (int i = t; i < 128; i += 256) bits[i] = tbits[i];
  __syncthreads();
  const int shft = (lane & 7) * 4;
#pragma unroll
  for (int g = 0; g < 2; ++g) {
    const int rl = w + 4 * g;            // local row 0..7
    const float4* srow = (const float4*)(src + (size_t)(r0 + rl) * K);
    float4 v[16];
    float am = 0.f;
#pragma unroll
    for (int j = 0; j < 16; ++j) {       // wave reads 1KB contiguous per instr
      float4 x = srow[j * 64 + lane];
      unsigned b4 = bits[j * 8 + (lane >> 3)] >> shft;
      if (!(b4 & 1u)) x.x = 0.f;
      if (!(b4 & 2u)) x.y = 0.f;
      if (!(b4 & 4u)) x.z = 0.f;
      if (!(b4 & 8u)) x.w = 0.f;
      v[j] = x;
      am = fmaxf(am, fmaxf(fmaxf(fabsf(x.x), fabsf(x.y)), fmaxf(fabsf(x.z), fabsf(x.w))));
    }
#pragma unroll
    for (int m = 1; m < 64; m <<= 1) am = fmaxf(am, __shfl_xor(am, m));
    const _Float16 sh = (_Float16)(am / 127.0f);   // RTN to fp16, like astype(float16)
    const float s = (float)sh;
    if (lane == 0) smax[r0 + rl] = sh;
    signed char* row = qt + rl * 4096;
#pragma unroll
    for (int j = 0; j < 16; ++j) {
      float4 x = v[j];
      char4 c;
      c.x = (signed char)(x.x / s);      // fp32 divide + trunc = astype(int8)
      c.y = (signed char)(x.y / s);
      c.z = (signed char)(x.z / s);
      c.w = (signed char)(x.w / s);
      const int c2 = j * 16 + (lane >> 2);
      *(char4*)(row + ((c2 ^ rl) << 4) + (lane & 3) * 4) = c;   // 2-way max (free)
    }
  }
  { // outlier gather first: scattered loads overlap the LDS store phase below
    const int j = t >> 3, rl = t & 7;
    unq[(size_t)j * R + r0 + rl] = src[(size_t)(r0 + rl) * K + idxg[j]];
  }
  __syncthreads();
  // store phase: 2048 int4, 128B-contiguous global segments
  const size_t pbase = (size_t)(r0 >> 5) * 32 * K + (size_t)(r0 & 31) * 16;
#pragma unroll
  for (int i = 0; i < 8; ++i) {
    const int s2 = i * 256 + t;
    const int c2 = s2 >> 3, rl = s2 & 7;
    int4 d = *(const int4*)(qt + rl * 4096 + ((c2 ^ rl) << 4));
    *(int4*)(q + pbase + (size_t)c2 * 512 + rl * 16) = d;
  }
}

// ---- kernel D: i8 GEMM, ring-3 LDS, in-wave pipelined fragment reads:
//      A-frags of tile kt+1 are read BEFORE the MFMA cluster of tile kt
//      (they land during the 16-MFMA cluster); B-frags just-in-time
//      (compiler counted lgkmcnt). At iter top the only outstanding VMEM is
//      S(kt+1), so vmcnt(0) there is a counted 1-body-lead wait; S(kt+2) is
//      issued after it and stays in flight. No setprio (m190).
__device__ __forceinline__ void gld_lds16(const signed char* g, signed char* l) {
  __builtin_amdgcn_global_load_lds(
      (const __attribute__((address_space(1))) void*)g,
      (__attribute__((address_space(3))) void*)l, 16, 0, 0);
}

__global__ __launch_bounds__(256, 2) void gemm_kernel(
    const signed char* __restrict__ xq, const signed char* __restrict__ wq,
    const _Float16* __restrict__ xmax, const _Float16* __restrict__ wmax,
    const float* __restrict__ xuf,   // [ALPHA][M]
    const float* __restrict__ wuf,   // [ALPHA][N]
    const float* __restrict__ bias,  // [N]
    float* __restrict__ out, int M, int N, int K) {
  __shared__ union {
    struct { signed char A[3][BM * BK]; signed char B[3][BN * BK]; } g;  // 72 KB ring-3
    struct { float xu[ALPHA * BM]; float wu[ALPHA * BN]; } e;            // 48 KB
  } sm;
  __shared__ _Float16 xmh[BM];
  __shared__ _Float16 wmh[BN];
  __shared__ float    bl[BN];

  const int t = threadIdx.x;
  // XCD-aware swizzle: 1024 blocks, 8 XCDs -> each XCD owns 4 consecutive bx.
  const int bid = blockIdx.y * gridDim.x + blockIdx.x;
  const int xcd = bid & 7, loc = bid >> 3;
  const int bxi = xcd * 4 + (loc & 3);
  const int byi = loc >> 2;
  const int bm0 = byi * BM;
  const int bn0 = bxi * BN;
  const int lane = t & 63, w = t >> 6;
  const int wm = w >> 1, wn = w & 1;       // 2x2 waves, wave tile 128x64
  const int hi = lane >> 5, l31 = lane & 31;

  i32x16 acc[4][2] = {};

  const size_t P32 = (size_t)32 * K;
  const signed char* aS = xq + (size_t)bm0 * K + (size_t)(t >> 7) * P32 + (t & 127) * 16;
  const signed char* bS = wq + (size_t)bn0 * K + (size_t)(t >> 7) * P32 + (t & 127) * 16;
  signed char* const aD = &sm.g.A[0][0] + t * 16;
  signed char* const bD = &sm.g.B[0][0] + t * 16;
  const signed char* const aR0 = &sm.g.A[0][0] + (wm * 4) * 2048 + 16 * lane;
  const signed char* const bR0 = &sm.g.B[0][0] + (wn * 2) * 2048 + 16 * lane;

#define STAGE(BUF, KT)                                                            \
  {                                                                               \
    const size_t ko = (size_t)(KT) * 2048;                                        \
    _Pragma("unroll") for (int i = 0; i < 4; ++i)                                 \
      gld_lds16(aS + (size_t)(2 * i) * P32 + ko, aD + (BUF) * (BM * BK) + i * 4096); \
    _Pragma("unroll") for (int i = 0; i < 2; ++i)                                 \
      gld_lds16(bS + (size_t)(2 * i) * P32 + ko, bD + (BUF) * (BN * BK) + i * 4096); \
  }

  // one K-tile body. AC = this tile's A-frags (read last body), AN = next tile's.
  // NOTE: macro-locals use trailing underscore so the CB argument expression
  // can safely reference loop-scope variables (r9 bug: self-init shadowing UB).
#define BODY(KT, AC, AN, CB)                                                      \
  {                                                                               \
    const int cb_ = (CB);                                                         \
    const int nb_ = (cb_ + 1 == 3) ? 0 : cb_ + 1;                                 \
    const int sb_ = (nb_ + 1 == 3) ? 0 : nb_ + 1;                                 \
    asm volatile("s_waitcnt vmcnt(0)" ::: "memory");   /* only S(KT+1) out */     \
    asm volatile("s_barrier" ::: "memory");                                       \
    i32x4 bf[2][2];                                                               \
    _Pragma("unroll") for (int ni = 0; ni < 2; ++ni)                              \
      _Pragma("unroll") for (int ks = 0; ks < 2; ++ks)                            \
        bf[ni][ks] = *(const i32x4*)(bR0 + cb_ * (BN * BK) + ni * 2048 + ks * 1024); \
    if ((KT) + 2 < NT) STAGE(sb_, (KT) + 2);                                      \
    if ((KT) + 1 < NT) {                                                          \
      _Pragma("unroll") for (int ks = 0; ks < 2; ++ks)                            \
        _Pragma("unroll") for (int mi = 0; mi < 4; ++mi)                          \
          AN[ks][mi] = *(const i32x4*)(aR0 + nb_ * (BM * BK) + mi * 2048 + ks * 1024); \
    }                                                                             \
    _Pragma("unroll") for (int ks = 0; ks < 2; ++ks)                              \
      _Pragma("unroll") for (int mi = 0; mi < 4; ++mi)                            \
        _Pragma("unroll") for (int ni = 0; ni < 2; ++ni)                          \
          acc[mi][ni] = __builtin_amdgcn_mfma_i32_32x32x32_i8(                    \
              AC[ks][mi], bf[ni][ks], acc[mi][ni], 0, 0, 0);                      \
  }

  const int NT = K >> 6;   // 64 (even)
  i32x4 aX[2][4], aY[2][4];
  STAGE(0, 0);
  STAGE(1, 1);
  asm volatile("s_waitcnt vmcnt(6)" ::: "memory");   // S(0) landed
  asm volatile("s_barrier" ::: "memory");
#pragma unroll
  for (int ks = 0; ks < 2; ++ks)
#pragma unroll
    for (int mi = 0; mi < 4; ++mi)
      aX[ks][mi] = *(const i32x4*)(aR0 + mi * 2048 + ks * 1024);

  int cb = 0;
  for (int kt = 0; kt < NT; kt += 2) {
    const int cbB = (cb + 1 == 3) ? 0 : cb + 1;
    BODY(kt,     aX, aY, cb);
    BODY(kt + 1, aY, aX, cbB);
    cb = (cb + 2) % 3;
  }
#undef BODY
#undef STAGE

  __syncthreads();
  // ---- epilogue staging (reuses GEMM LDS) ----
  {
    const float4* xs = (const float4*)xuf;
    float4* xl = (float4*)sm.e.xu;
#pragma unroll
    for (int i = 0; i < 8; ++i) {   // 2048 float4
      int p = i * 256 + t;
      int j = p >> 6, r4 = p & 63;
      xl[p] = xs[(size_t)j * (M >> 2) + (bm0 >> 2) + r4];
    }
    const float4* wsrc = (const float4*)wuf;
    float4* wl = (float4*)sm.e.wu;
#pragma unroll
    for (int i = 0; i < 4; ++i) {   // 1024 float4
      int p = i * 256 + t;
      int j = p >> 5, r4 = p & 31;
      wl[p] = wsrc[(size_t)j * (N >> 2) + (bn0 >> 2) + r4];
    }
    if (t < BM / 2) ((unsigned*)xmh)[t] = ((const unsigned*)(xmax + bm0))[t];
    if (t < BN / 2) ((unsigned*)wmh)[t] = ((const unsigned*)(wmax + bn0))[t];
    if (t < BN / 4) ((float4*)bl)[t] = ((const float4*)(bias + bn0))[t];
  }
  __syncthreads();

  const int c0 = wn * 64 + l31;   // column (within tile) for ni=0; ni=1 is +32
  const _Float16 wh0 = wmh[c0], wh1 = wmh[c0 + 32];
  const float bv0 = bl[c0], bv1 = bl[c0 + 32];
  const float* xul = sm.e.xu;     // [ALPHA][BM]
  const float* wul = sm.e.wu;     // [ALPHA][BN]

#pragma unroll
  for (int mi = 0; mi < 4; ++mi) {
    const int rbase = wm * 128 + mi * 32 + 4 * hi;   // + (r&3) + 8*(r>>2)
    float f0[16], f1[16];
#pragma unroll
    for (int r = 0; r < 16; ++r) {
      int row = rbase + (r & 3) + 8 * (r >> 2);
      _Float16 xh = xmh[row];
      float mx0 = (float)(_Float16)(xh * wh0);   // fp16 multiply (subnormal-correct) like ref
      float mx1 = (float)(_Float16)(xh * wh1);
      f0[r] = (float)acc[mi][0][r] * mx0 + bv0;
      f1[r] = (float)acc[mi][1][r] * mx1 + bv1;
    }
#pragma unroll 4
    for (int j = 0; j < ALPHA; ++j) {            // rank-32 fp32 outlier update
      const float4* xrow4 = (const float4*)(xul + j * BM + rbase);
      float wv0 = wul[j * BN + c0];
      float wv1 = wul[j * BN + c0 + 32];
#pragma unroll
      for (int gq = 0; gq < 4; ++gq) {
        float4 xv = xrow4[gq * 2];               // rows rbase + 8*gq .. +3
        f0[gq * 4 + 0] += xv.x * wv0;  f1[gq * 4 + 0] += xv.x * wv1;
        f0[gq * 4 + 1] += xv.y * wv0;  f1[gq * 4 + 1] += xv.y * wv1;
        f0[gq * 4 + 2] += xv.z * wv0;  f1[gq * 4 + 2] += xv.z * wv1;
        f0[gq * 4 + 3] += xv.w * wv0;  f1[gq * 4 + 3] += xv.w * wv1;
      }
    }
#pragma unroll
    for (int r = 0; r < 16; ++r) {
      int row = bm0 + rbase + (r & 3) + 8 * (r >> 2);
      size_t o = (size_t)row * N + bn0;
      out[o + c0] = f0[r];
      out[o + c0 + 32] = f1[r];
    }
  }
}

// ---------------- launch ----------------
extern "C" void kernel_launch(void* const* d_in, const int* in_sizes, int n_in,
                              void* d_out, int out_size, void* d_ws, size_t ws_size,
                              hipStream_t stream) {
  const float* x       = (const float*)d_in[0];
  const float* W       = (const float*)d_in[1];
  const float* bias    = (const float*)d_in[2];
  const float* act_max = (const float*)d_in[3];
  const int K = in_sizes[3];            // 4096
  const int N = in_sizes[1] / K;        // 4096
  const int M = in_sizes[0] / K;        // 8192
  float* out = (float*)d_out;

  char* ws = (char*)d_ws;
  size_t off = 0;
  auto take = [&](size_t b) { char* p = ws + off; off += (b + 255) & ~(size_t)255; return p; };
  signed char* wq  = (signed char*)take((size_t)N * K);
  signed char* xq  = (signed char*)take((size_t)M * K);
  _Float16* wmax   = (_Float16*)take((size_t)N * 2);
  _Float16* xmax   = (_Float16*)take((size_t)M * 2);
  float* wuf       = (float*)take((size_t)ALPHA * N * 4);
  float* xuf       = (float*)take((size_t)ALPHA * M * 4);
  int* idx         = (int*)take(ALPHA * 4);
  unsigned* tbits  = (unsigned*)take((size_t)(K / 32) * 4);

  const int nbw = N / 8, nbx = M / 8;   // 512 + 1024 = 1536 blocks
  topk_kernel<<<1, 256, 0, stream>>>(act_max, idx, tbits, K);
  quant8_kernel<<<nbw + nbx, 256, 0, stream>>>(W, x, tbits, idx, wq, xq,
                                               wmax, xmax, wuf, xuf, nbw, K, N, M);
  dim3 grid(N / BN, M / BM);
  gemm_kernel<<<grid, 256, 0, stream>>>(xq, wq, xmax, wmax, xuf, wuf, bias, out, M, N, K);
}

// Round 11
// 254.293 us; speedup vs baseline: 1.1481x; 1.1382x over previous
//
#include <hip/hip_runtime.h>
#include <hip/hip_fp16.h>

typedef __attribute__((ext_vector_type(4)))  int   i32x4;
typedef __attribute__((ext_vector_type(16))) int   i32x16;

#define ALPHA 32
#define BM 256
#define BN 128
#define BK 64

// Tiled int8 workspace layout (matches LDS staging & fragment reads):
//   addr(row,k) = (row>>5)*(32*K) + (k>>4)*512 + (row&31)*16 + (k&15)

// ---------------- kernel A: top-32 of |act_max| + keep-bitmask ----------------
// Candidates live in registers (16/thread); cleared by compile-time-indexed
// compare (rule 20: no dynamic register indexing).
__global__ __launch_bounds__(256) void topk_kernel(const float* __restrict__ act_max,
                                                   int* __restrict__ idx_out,
                                                   unsigned* __restrict__ tbits,
                                                   int K) {
  __shared__ float rv[4];
  __shared__ int   ri[4];
  __shared__ unsigned bits[128];
  __shared__ int bsel;
  const int t = threadIdx.x, w = t >> 6;
  float vloc[16];
#pragma unroll
  for (int jj = 0; jj < 16; ++jj) vloc[jj] = fabsf(act_max[jj * 256 + t]);
  for (int i = t; i < 128; i += 256) bits[i] = 0xFFFFFFFFu;
  __syncthreads();
  for (int sel = 0; sel < ALPHA; ++sel) {
    float bv = vloc[0]; int bi = t;          // ascending scan keeps lowest index on ties
#pragma unroll
    for (int jj = 1; jj < 16; ++jj)
      if (vloc[jj] > bv) { bv = vloc[jj]; bi = jj * 256 + t; }
    for (int m = 1; m < 64; m <<= 1) {
      float ov = __shfl_xor(bv, m);
      int   oi = __shfl_xor(bi, m);
      if (ov > bv || (ov == bv && oi < bi)) { bv = ov; bi = oi; }
    }
    if ((t & 63) == 0) { rv[w] = bv; ri[w] = bi; }
    __syncthreads();
    if (t == 0) {
      for (int u = 1; u < 4; ++u)
        if (rv[u] > bv || (rv[u] == bv && ri[u] < bi)) { bv = rv[u]; bi = ri[u]; }
      idx_out[sel] = bi;
      bits[bi >> 5] &= ~(1u << (bi & 31));
      bsel = bi;
    }
    __syncthreads();
    const int bs = bsel;
#pragma unroll
    for (int jj = 0; jj < 16; ++jj)
      if (jj * 256 + t == bs) vloc[jj] = -2.f;
    __syncthreads();
  }
  for (int i = t; i < 128; i += 256) tbits[i] = bits[i];
}

// ------------- kernel B: 12-rows-per-block quantization + gather -------------
// 1024 blocks exactly (one full-occupancy round, no tail). Global row space:
// [0,N) = W rows, [N,N+M) = x rows. 3 phases of 4 rows (one row per wave):
// coalesced reads -> per-wave max -> quantize via x*(1/s) -> 16KB swizzled LDS
// bounce -> tiled-layout stores as 128B-contiguous segments.
__global__ __launch_bounds__(256) void quant12_kernel(
    const float* __restrict__ srcW, const float* __restrict__ srcX,
    const unsigned* __restrict__ tbits, const int* __restrict__ idxg,
    signed char* __restrict__ wq, signed char* __restrict__ xq,
    _Float16* __restrict__ wmax, _Float16* __restrict__ xmax,
    float* __restrict__ wuf, float* __restrict__ xuf,
    int K, int N, int M) {
  const int t = threadIdx.x, lane = t & 63, w = t >> 6;
  const int r0 = blockIdx.x * 12;
  __shared__ unsigned bits[128];
  __shared__ signed char qt[4 * 4096];   // 16 KB bounce (4 rows/phase)
  for (int i = t; i < 128; i += 256) bits[i] = tbits[i];
  __syncthreads();
  const int shft = (lane & 7) * 4;
#pragma unroll
  for (int g = 0; g < 3; ++g) {
    const int r = r0 + g * 4 + w;                       // this wave's global row
    const bool isW = r < N;                             // wave-uniform
    const float* srow = isW ? (srcW + (size_t)r * K) : (srcX + (size_t)(r - N) * K);
    const float4* srow4 = (const float4*)srow;
    float4 v[16];
    float am = 0.f;
#pragma unroll
    for (int j = 0; j < 16; ++j) {       // wave reads 1KB contiguous per instr
      float4 x = srow4[j * 64 + lane];
      unsigned b4 = bits[j * 8 + (lane >> 3)] >> shft;
      if (!(b4 & 1u)) x.x = 0.f;
      if (!(b4 & 2u)) x.y = 0.f;
      if (!(b4 & 4u)) x.z = 0.f;
      if (!(b4 & 8u)) x.w = 0.f;
      v[j] = x;
      am = fmaxf(am, fmaxf(fmaxf(fabsf(x.x), fabsf(x.y)), fmaxf(fabsf(x.z), fabsf(x.w))));
    }
#pragma unroll
    for (int m = 1; m < 64; m <<= 1) am = fmaxf(am, __shfl_xor(am, m));
    const _Float16 sh = (_Float16)(am / 127.0f);   // RTN to fp16, like astype(float16)
    const float inv = 1.0f / (float)sh;            // one exact divide per row
    if (lane == 0) { if (isW) wmax[r] = sh; else xmax[r - N] = sh; }
    signed char* rowq = qt + w * 4096;
#pragma unroll
    for (int j = 0; j < 16; ++j) {
      float4 x = v[j];
      char4 c;
      c.x = (signed char)(x.x * inv);    // rcp-mul + trunc (audited: <=1ulp vs div)
      c.y = (signed char)(x.y * inv);
      c.z = (signed char)(x.z * inv);
      c.w = (signed char)(x.w * inv);
      const int c2 = j * 16 + (lane >> 2);
      *(char4*)(rowq + ((c2 ^ w) << 4) + (lane & 3) * 4) = c;   // 2-way max (free)
    }
    __syncthreads();
    // store phase: 1024 int4 (4 rows x 256 chunks), 128B-contiguous segments
#pragma unroll
    for (int i = 0; i < 4; ++i) {
      const int s2 = i * 256 + t;
      const int c2 = s2 >> 2, rl = s2 & 3;
      const int row = r0 + g * 4 + rl;                 // never straddles a 32-panel
      int4 d = *(const int4*)(qt + rl * 4096 + ((c2 ^ rl) << 4));
      signed char* q = (row < N) ? wq : xq;
      const int rr = (row < N) ? row : row - N;
      *(int4*)(q + (size_t)(rr >> 5) * 32 * K + (size_t)c2 * 512 + (rr & 31) * 16) = d;
    }
    __syncthreads();
  }
  // outlier gather: 32 idx x 12 rows = 384 scattered floats
  for (int p = t; p < 32 * 12; p += 256) {
    const int lr = p >> 5, j = p & 31;
    const int row = r0 + lr;
    if (row < N) wuf[(size_t)j * N + row]       = srcW[(size_t)row * K + idxg[j]];
    else         xuf[(size_t)j * M + (row - N)] = srcX[(size_t)(row - N) * K + idxg[j]];
  }
}

// ---- kernel D: i8 GEMM (round-5 verbatim: 3-buf ring, 2-deep prefetch,
//      counted vmcnt(6), peeled tail, setprio) -- measured 177 us / 37% ----
__device__ __forceinline__ void gld_lds16(const signed char* g, signed char* l) {
  __builtin_amdgcn_global_load_lds(
      (const __attribute__((address_space(1))) void*)g,
      (__attribute__((address_space(3))) void*)l, 16, 0, 0);
}

__global__ __launch_bounds__(256, 2) void gemm_kernel(
    const signed char* __restrict__ xq, const signed char* __restrict__ wq,
    const _Float16* __restrict__ xmax, const _Float16* __restrict__ wmax,
    const float* __restrict__ xuf,   // [ALPHA][M]
    const float* __restrict__ wuf,   // [ALPHA][N]
    const float* __restrict__ bias,  // [N]
    float* __restrict__ out, int M, int N, int K) {
  __shared__ union {
    struct { signed char A[3][BM * BK]; signed char B[3][BN * BK]; } g;  // 72 KB, 3-buf
    struct { float xu[ALPHA * BM]; float wu[ALPHA * BN]; } e;            // 48 KB
  } sm;
  __shared__ _Float16 xmh[BM];
  __shared__ _Float16 wmh[BN];
  __shared__ float    bl[BN];

  const int t = threadIdx.x;
  // XCD-aware swizzle: 1024 blocks, 8 XCDs -> each XCD owns 4 consecutive bx.
  const int bid = blockIdx.y * gridDim.x + blockIdx.x;
  const int xcd = bid & 7, loc = bid >> 3;
  const int bxi = xcd * 4 + (loc & 3);
  const int byi = loc >> 2;
  const int bm0 = byi * BM;
  const int bn0 = bxi * BN;
  const int lane = t & 63, w = t >> 6;
  const int wm = w >> 1, wn = w & 1;       // 2x2 waves, wave tile 128x64
  const int hi = lane >> 5, l31 = lane & 31;

  i32x16 acc[4][2] = {};

  const int tp = t >> 7;                  // panel parity within an issue
  const int to = (t & 127) * 16;
  const signed char* aS = xq + (size_t)bm0 * K + (size_t)tp * 32 * K + to;
  const signed char* bS = wq + (size_t)bn0 * K + (size_t)tp * 32 * K + to;
  signed char* const aD = &sm.g.A[0][0] + t * 16;
  signed char* const bD = &sm.g.B[0][0] + t * 16;
  const size_t PSTR = (size_t)64 * K;     // 2-panel stride

  auto STAGE = [&](int buf, int kt) {
    const size_t ko = (size_t)kt * 2048;  // (kt*64)>>4 * 512
#pragma unroll
    for (int i = 0; i < 4; ++i)
      gld_lds16(aS + (size_t)i * PSTR + ko, aD + buf * (BM * BK) + i * 4096);
#pragma unroll
    for (int i = 0; i < 2; ++i)
      gld_lds16(bS + (size_t)i * PSTR + ko, bD + buf * (BN * BK) + i * 4096);
  };

  const int NT = K >> 6;   // 64
  STAGE(0, 0);
  STAGE(1, 1);
  const signed char* const aR0 = &sm.g.A[0][0] + (wm * 4) * 2048 + 16 * lane;
  const signed char* const bR0 = &sm.g.B[0][0] + (wn * 2) * 2048 + 16 * lane;

  int cur = 0, st = 2;
  for (int kt = 0; kt < NT - 1; ++kt) {
    // tile kt's loads were issued 2 iters ago: counted wait, never drain to 0.
    asm volatile("s_waitcnt vmcnt(6)" ::: "memory");
    asm volatile("s_barrier" ::: "memory");
    const signed char* aRd = aR0 + cur * (BM * BK);
    const signed char* bRd = bR0 + cur * (BN * BK);
    i32x4 af[2][4], bf[2][2];
#pragma unroll
    for (int ks = 0; ks < 2; ++ks) {
#pragma unroll
      for (int mi = 0; mi < 4; ++mi) af[ks][mi] = *(const i32x4*)(aRd + mi * 2048 + ks * 1024);
#pragma unroll
      for (int ni = 0; ni < 2; ++ni) bf[ks][ni] = *(const i32x4*)(bRd + ni * 2048 + ks * 1024);
    }
    if (kt + 2 < NT) STAGE(st, kt + 2);   // 2-deep prefetch
    __builtin_amdgcn_s_setprio(1);
#pragma unroll
    for (int ks = 0; ks < 2; ++ks)
#pragma unroll
      for (int mi = 0; mi < 4; ++mi)
#pragma unroll
        for (int ni = 0; ni < 2; ++ni)
          acc[mi][ni] = __builtin_amdgcn_mfma_i32_32x32x32_i8(af[ks][mi], bf[ks][ni], acc[mi][ni], 0, 0, 0);
    __builtin_amdgcn_s_setprio(0);
    if (++cur == 3) cur = 0;
    if (++st == 3) st = 0;
  }
  { // peeled last tile: only here do we drain
    asm volatile("s_waitcnt vmcnt(0)" ::: "memory");
    asm volatile("s_barrier" ::: "memory");
    const signed char* aRd = aR0 + cur * (BM * BK);
    const signed char* bRd = bR0 + cur * (BN * BK);
    i32x4 af[2][4], bf[2][2];
#pragma unroll
    for (int ks = 0; ks < 2; ++ks) {
#pragma unroll
      for (int mi = 0; mi < 4; ++mi) af[ks][mi] = *(const i32x4*)(aRd + mi * 2048 + ks * 1024);
#pragma unroll
      for (int ni = 0; ni < 2; ++ni) bf[ks][ni] = *(const i32x4*)(bRd + ni * 2048 + ks * 1024);
    }
    __builtin_amdgcn_s_setprio(1);
#pragma unroll
    for (int ks = 0; ks < 2; ++ks)
#pragma unroll
      for (int mi = 0; mi < 4; ++mi)
#pragma unroll
        for (int ni = 0; ni < 2; ++ni)
          acc[mi][ni] = __builtin_amdgcn_mfma_i32_32x32x32_i8(af[ks][mi], bf[ks][ni], acc[mi][ni], 0, 0, 0);
    __builtin_amdgcn_s_setprio(0);
  }

  __syncthreads();
  // ---- epilogue staging (reuses GEMM LDS) ----
  {
    const float4* xs = (const float4*)xuf;
    float4* xl = (float4*)sm.e.xu;
#pragma unroll
    for (int i = 0; i < 8; ++i) {   // 2048 float4
      int p = i * 256 + t;
      int j = p >> 6, r4 = p & 63;
      xl[p] = xs[(size_t)j * (M >> 2) + (bm0 >> 2) + r4];
    }
    const float4* wsrc = (const float4*)wuf;
    float4* wl = (float4*)sm.e.wu;
#pragma unroll
    for (int i = 0; i < 4; ++i) {   // 1024 float4
      int p = i * 256 + t;
      int j = p >> 5, r4 = p & 31;
      wl[p] = wsrc[(size_t)j * (N >> 2) + (bn0 >> 2) + r4];
    }
    if (t < BM / 2) ((unsigned*)xmh)[t] = ((const unsigned*)(xmax + bm0))[t];
    if (t < BN / 2) ((unsigned*)wmh)[t] = ((const unsigned*)(wmax + bn0))[t];
    if (t < BN / 4) ((float4*)bl)[t] = ((const float4*)(bias + bn0))[t];
  }
  __syncthreads();

  const int c0 = wn * 64 + l31;   // column (within tile) for ni=0; ni=1 is +32
  const _Float16 wh0 = wmh[c0], wh1 = wmh[c0 + 32];
  const float bv0 = bl[c0], bv1 = bl[c0 + 32];
  const float* xul = sm.e.xu;     // [ALPHA][BM]
  const float* wul = sm.e.wu;     // [ALPHA][BN]

#pragma unroll
  for (int mi = 0; mi < 4; ++mi) {
    const int rbase = wm * 128 + mi * 32 + 4 * hi;   // + (r&3) + 8*(r>>2)
    float f0[16], f1[16];
#pragma unroll
    for (int r = 0; r < 16; ++r) {
      int row = rbase + (r & 3) + 8 * (r >> 2);
      _Float16 xh = xmh[row];
      float mx0 = (float)(_Float16)(xh * wh0);   // fp16 multiply (subnormal-correct) like ref
      float mx1 = (float)(_Float16)(xh * wh1);
      f0[r] = (float)acc[mi][0][r] * mx0 + bv0;
      f1[r] = (float)acc[mi][1][r] * mx1 + bv1;
    }
#pragma unroll 4
    for (int j = 0; j < ALPHA; ++j) {            // rank-32 fp32 outlier update
      const float4* xrow4 = (const float4*)(xul + j * BM + rbase);
      float wv0 = wul[j * BN + c0];
      float wv1 = wul[j * BN + c0 + 32];
#pragma unroll
      for (int gq = 0; gq < 4; ++gq) {
        float4 xv = xrow4[gq * 2];               // rows rbase + 8*gq .. +3
        f0[gq * 4 + 0] += xv.x * wv0;  f1[gq * 4 + 0] += xv.x * wv1;
        f0[gq * 4 + 1] += xv.y * wv0;  f1[gq * 4 + 1] += xv.y * wv1;
        f0[gq * 4 + 2] += xv.z * wv0;  f1[gq * 4 + 2] += xv.z * wv1;
        f0[gq * 4 + 3] += xv.w * wv0;  f1[gq * 4 + 3] += xv.w * wv1;
      }
    }
#pragma unroll
    for (int r = 0; r < 16; ++r) {
      int row = bm0 + rbase + (r & 3) + 8 * (r >> 2);
      size_t o = (size_t)row * N + bn0;
      out[o + c0] = f0[r];
      out[o + c0 + 32] = f1[r];
    }
  }
}

// ---------------- launch ----------------
extern "C" void kernel_launch(void* const* d_in, const int* in_sizes, int n_in,
                              void* d_out, int out_size, void* d_ws, size_t ws_size,
                              hipStream_t stream) {
  const float* x       = (const float*)d_in[0];
  const float* W       = (const float*)d_in[1];
  const float* bias    = (const float*)d_in[2];
  const float* act_max = (const float*)d_in[3];
  const int K = in_sizes[3];            // 4096
  const int N = in_sizes[1] / K;        // 4096
  const int M = in_sizes[0] / K;        // 8192
  float* out = (float*)d_out;

  char* ws = (char*)d_ws;
  size_t off = 0;
  auto take = [&](size_t b) { char* p = ws + off; off += (b + 255) & ~(size_t)255; return p; };
  signed char* wq  = (signed char*)take((size_t)N * K);
  signed char* xq  = (signed char*)take((size_t)M * K);
  _Float16* wmax   = (_Float16*)take((size_t)N * 2);
  _Float16* xmax   = (_Float16*)take((size_t)M * 2);
  float* wuf       = (float*)take((size_t)ALPHA * N * 4);
  float* xuf       = (float*)take((size_t)ALPHA * M * 4);
  int* idx         = (int*)take(ALPHA * 4);
  unsigned* tbits  = (unsigned*)take((size_t)(K / 32) * 4);

  topk_kernel<<<1, 256, 0, stream>>>(act_max, idx, tbits, K);
  quant12_kernel<<<(N + M) / 12, 256, 0, stream>>>(W, x, tbits, idx, wq, xq,
                                                   wmax, xmax, wuf, xuf, K, N, M);
  dim3 grid(N / BN, M / BM);
  gemm_kernel<<<grid, 256, 0, stream>>>(xq, wq, xmax, wmax, xuf, wuf, bias, out, M, N, K);
}